// Round 10
// baseline (2842.564 us; speedup 1.0000x reference)
//
#include <hip/hip_runtime.h>
#include <math.h>

#define NFFT   1024
#define NHALF  512
#define HOPSZ  256
#define NMELS  80
#define NFREQ  513
#define BATCH  8
#define TFRAMES 1024
#define PADW   512
#define LPAD   (NFFT + (TFRAMES - 1) * HOPSZ)   // 262912
#define LOUT   (LPAD - 2 * PADW)                // 261888
#define NITER  60
#define PI_D   3.14159265358979323846

#define CHUNKF 4                                // frames per chunk
#define CSPAN  1792                             // 1024 + 3*256
#define NCHUNK (TFRAMES / CHUNKF)               // 256

// padding for the (old, init-only) radix-4 FFT
#define PAD(p) ((p) + ((p) >> 5))
#define NPAD   (NHALF + (NHALF >> 5))           // 528

// padding for the hot-loop radix-8 C buffer (float2 units): +1 per 8
#define PC(p)  ((p) + ((p) >> 3))
#define C_SZ   576                              // PC(511)=574 < 576

// ---------------------------------------------------------------- init tables
__global__ void k_init_tables(float* __restrict__ twr, float* __restrict__ twi,
                              float* __restrict__ t5r, float* __restrict__ t5i,
                              float* __restrict__ win) {
    int j = blockIdx.x * 256 + threadIdx.x;
    if (j < NHALF) {
        double th = -2.0 * PI_D * (double)j / (double)NFFT;
        twr[j] = (float)cos(th);
        twi[j] = (float)sin(th);
    }
    if (j < 128) {
        double th = -2.0 * PI_D * (double)j / 512.0;
        t5r[j] = (float)cos(th);
        t5i[j] = (float)sin(th);
    }
    if (j < NFFT) {
        win[j] = (float)(0.5 - 0.5 * cos(2.0 * PI_D * (double)j / (double)NFFT));
    }
}

__global__ void k_env(const float* __restrict__ win, float* __restrict__ envinv) {
    int i = blockIdx.x * 256 + threadIdx.x;
    if (i >= LPAD) return;
    int thi = i / HOPSZ; if (thi > TFRAMES - 1) thi = TFRAMES - 1;
    int d = i - (NFFT - 1);
    int tlo = (d > 0) ? (d + HOPSZ - 1) / HOPSZ : 0;
    float e = 0.f;
    for (int t = tlo; t <= thi; ++t) { float w = win[i - t * HOPSZ]; e += w * w; }
    envinv[i] = (e > 1e-11f) ? (1.0f / e) : 1.0f;
}

__global__ void k_fbt(const float* __restrict__ fb, float* __restrict__ fbT) {
    int i = blockIdx.x * 256 + threadIdx.x;
    if (i < NFREQ * NMELS) {
        int k = i / NMELS, m = i - k * NMELS;
        fbT[m * NFREQ + k] = fb[i];
    }
}

// mag[(b*1024+t)*513+k], tiled 16 t per block
__global__ __launch_bounds__(256) void k_mag(const float* __restrict__ mel,
                                             const float* __restrict__ fbT,
                                             float* __restrict__ mag) {
    __shared__ float sm[NMELS * 16];
    int b = blockIdx.y, t0 = blockIdx.x * 16, tid = threadIdx.x;
    for (int idx = tid; idx < NMELS * 16; idx += 256) {
        int m = idx >> 4, tt = idx & 15;
        sm[idx] = expf(mel[(size_t)(b * NMELS + m) * TFRAMES + (t0 + tt)]);
    }
    __syncthreads();
    for (int k = tid; k < NFREQ; k += 256) {
        float acc[16];
        #pragma unroll
        for (int tt = 0; tt < 16; ++tt) acc[tt] = 0.f;
        for (int m = 0; m < NMELS; ++m) {
            float w = fbT[m * NFREQ + k];
            #pragma unroll
            for (int tt = 0; tt < 16; ++tt) acc[tt] += w * sm[m * 16 + tt];
        }
        #pragma unroll
        for (int tt = 0; tt < 16; ++tt)
            mag[(size_t)((b << 10) + t0 + tt) * NFREQ + k] = fmaxf(acc[tt], 0.f);
    }
}

// ===================== old radix-4 path (init kernel only, verified round 6)
__device__ __forceinline__ void fft512_m(float* xr, float* xi, float* yr, float* yi,
                                         const float* t5r, const float* t5i,
                                         int l, float sgn) {
    float *ar = xr, *ai = xi, *br = yr, *bi = yi;
    #pragma unroll
    for (int st = 0; st < 4; ++st) {
        int s = 1 << (2 * st);
        __syncthreads();
        int j = l;
        int hi = j & ~(s - 1);
        int o1 = j + 3 * hi;
        float v0r = ar[PAD(j)],       v0i = ai[PAD(j)];
        float v1r = ar[PAD(j + 128)], v1i = ai[PAD(j + 128)];
        float v2r = ar[PAD(j + 256)], v2i = ai[PAD(j + 256)];
        float v3r = ar[PAD(j + 384)], v3i = ai[PAD(j + 384)];
        float a_r = v0r + v2r, a_i = v0i + v2i;
        float b_r = v0r - v2r, b_i = v0i - v2i;
        float c_r = v1r + v3r, c_i = v1i + v3i;
        float d_r = v1r - v3r, d_i = v1i - v3i;
        float X0r = a_r + c_r, X0i = a_i + c_i;
        float X2r = a_r - c_r, X2i = a_i - c_i;
        float X1r = b_r + sgn * d_i, X1i = b_i - sgn * d_r;
        float X3r = b_r - sgn * d_i, X3i = b_i + sgn * d_r;
        float w1r = t5r[hi], w1i = sgn * t5i[hi];
        float w2r = w1r * w1r - w1i * w1i, w2i = 2.f * w1r * w1i;
        float w3r = w2r * w1r - w2i * w1i, w3i = w2r * w1i + w2i * w1r;
        br[PAD(o1)]         = X0r;
        bi[PAD(o1)]         = X0i;
        br[PAD(o1 + s)]     = X1r * w1r - X1i * w1i;
        bi[PAD(o1 + s)]     = X1r * w1i + X1i * w1r;
        br[PAD(o1 + 2*s)]   = X2r * w2r - X2i * w2i;
        bi[PAD(o1 + 2*s)]   = X2r * w2i + X2i * w2r;
        br[PAD(o1 + 3*s)]   = X3r * w3r - X3i * w3i;
        bi[PAD(o1 + 3*s)]   = X3r * w3i + X3i * w3r;
        float* t0 = ar; ar = br; br = t0;
        float* t1 = ai; ai = bi; bi = t1;
    }
    __syncthreads();
    #pragma unroll
    for (int r = 0; r < 2; ++r) {
        int j = l + r * 128;
        float x0r = ar[PAD(j)],       x0i = ai[PAD(j)];
        float x1r = ar[PAD(j + 256)], x1i = ai[PAD(j + 256)];
        br[PAD(j)]       = x0r + x1r;
        bi[PAD(j)]       = x0i + x1i;
        br[PAD(j + 256)] = x0r - x1r;
        bi[PAD(j + 256)] = x0i - x1i;
    }
}

__device__ __forceinline__ void chunk_ola4(float (*Yr)[NPAD], float (*Yi)[NPAD],
                                           const float* swin, float* Po, int tid) {
    const float SC = 1.0f / 512.0f;
    for (int j = tid; j < CSPAN; j += 512) {
        float acc = 0.f;
        #pragma unroll
        for (int gg = 0; gg < CHUNKF; ++gg) {
            int p = j - 256 * gg;
            if (p >= 0 && p < NFFT) {
                float yv = (p & 1) ? Yi[gg][PAD(p >> 1)] : Yr[gg][PAD(p >> 1)];
                acc += yv * swin[p];
            }
        }
        Po[j] = acc * SC;
    }
}

// -------------------- init: P0 from mag * e^{i 2pi ang} (verified round 6)
__global__ __launch_bounds__(512) void k_init4(
        const float* __restrict__ mag, const float* __restrict__ ang,
        const float* __restrict__ gtwr, const float* __restrict__ gtwi,
        const float* __restrict__ gt5r, const float* __restrict__ gt5i,
        const float* __restrict__ win, float* __restrict__ Pout) {
    __shared__ float swin[NFFT];
    __shared__ float Xr[CHUNKF][NPAD], Xi[CHUNKF][NPAD];
    __shared__ float Yr[CHUNKF][NPAD], Yi[CHUNKF][NPAD];
    __shared__ float t5r[128], t5i[128];
    int blk = blockIdx.x; int b = blk >> 8; int c = blk & (NCHUNK - 1);
    int tid = threadIdx.x; int g = tid >> 7; int l = tid & 127;
    if (tid < 128) { t5r[tid] = gt5r[tid]; t5i[tid] = gt5i[tid]; }
    for (int q = tid; q < NFFT; q += 512) swin[q] = win[q];
    int ft = CHUNKF * c + g;
    const float* mrow = mag + (size_t)(b * TFRAMES + ft) * NFREQ;
    const float TWO_PI = 6.283185307179586477f;
    if (l == 0) {
        float a0, s0, c0;
        a0 = ang[((size_t)(b * NFREQ + 0)) * TFRAMES + ft] * TWO_PI;
        sincosf(a0, &s0, &c0);
        float p0 = mrow[0] * c0;
        a0 = ang[((size_t)(b * NFREQ + 512)) * TFRAMES + ft] * TWO_PI;
        sincosf(a0, &s0, &c0);
        float p512 = mrow[512] * c0;
        Xr[g][PAD(0)] = 0.5f * (p0 + p512);
        Xi[g][PAD(0)] = 0.5f * (p0 - p512);
        a0 = ang[((size_t)(b * NFREQ + 256)) * TFRAMES + ft] * TWO_PI;
        sincosf(a0, &s0, &c0);
        Xr[g][PAD(256)] = mrow[256] * c0;
        Xi[g][PAD(256)] = -(mrow[256] * s0);
    }
    #pragma unroll
    for (int q2 = 0; q2 < 2; ++q2) {
        int k = l + q2 * 128;
        if (k == 0) continue;
        int j = 512 - k;
        float ak = ang[((size_t)(b * NFREQ + k)) * TFRAMES + ft] * TWO_PI;
        float aj = ang[((size_t)(b * NFREQ + j)) * TFRAMES + ft] * TWO_PI;
        float sk, ck, sj, cj;
        sincosf(ak, &sk, &ck); sincosf(aj, &sj, &cj);
        float pkr = mrow[k] * ck, pki = mrow[k] * sk;
        float pjr = mrow[j] * cj, pji = mrow[j] * sj;
        float Wr = gtwr[k], Wi = gtwi[k];
        float Cr = 0.5f * (pkr + pjr), Ci = 0.5f * (pki - pji);
        float Dr = 0.5f * (pkr - pjr), Di = 0.5f * (pki + pji);
        float U = Wr * Di - Wi * Dr, V = Wr * Dr + Wi * Di;
        Xr[g][PAD(k)] = Cr - U;  Xi[g][PAD(k)] = Ci + V;
        Xr[g][PAD(j)] = Cr + U;  Xi[g][PAD(j)] = -Ci + V;
    }
    fft512_m(Xr[g], Xi[g], Yr[g], Yi[g], t5r, t5i, l, -1.f);
    __syncthreads();
    chunk_ola4(Yr, Yi, swin, Pout + ((size_t)b * NCHUNK + c) * CSPAN, tid);
}

// ===================== wave-local radix-8 machinery (hot loop) ==============
__device__ __forceinline__ float2 cmul(float2 a, float2 b) {
    return make_float2(a.x * b.x - a.y * b.y, a.x * b.y + a.y * b.x);
}

// in-register 8-pt DFT; sgn=+1 forward, -1 inverse (verified round 7)
__device__ __forceinline__ void dft8(float2 v[8], float sgn) {
    const float s2 = 0.70710678118654752f;
    float ar = v[0].x + v[4].x, ai = v[0].y + v[4].y;
    float br = v[0].x - v[4].x, bi = v[0].y - v[4].y;
    float cr = v[2].x + v[6].x, ci = v[2].y + v[6].y;
    float dr = v[2].x - v[6].x, di = v[2].y - v[6].y;
    float2 E0 = make_float2(ar + cr, ai + ci);
    float2 E2 = make_float2(ar - cr, ai - ci);
    float2 E1 = make_float2(br + sgn * di, bi - sgn * dr);
    float2 E3 = make_float2(br - sgn * di, bi + sgn * dr);
    float ar2 = v[1].x + v[5].x, ai2 = v[1].y + v[5].y;
    float br2 = v[1].x - v[5].x, bi2 = v[1].y - v[5].y;
    float cr2 = v[3].x + v[7].x, ci2 = v[3].y + v[7].y;
    float dr2 = v[3].x - v[7].x, di2 = v[3].y - v[7].y;
    float2 O0 = make_float2(ar2 + cr2, ai2 + ci2);
    float2 O2 = make_float2(ar2 - cr2, ai2 - ci2);
    float2 O1 = make_float2(br2 + sgn * di2, bi2 - sgn * dr2);
    float2 O3 = make_float2(br2 - sgn * di2, bi2 + sgn * dr2);
    float2 T1 = make_float2((O1.x + sgn * O1.y) * s2, (O1.y - sgn * O1.x) * s2);
    float2 T2 = make_float2(sgn * O2.y, -sgn * O2.x);
    float2 T3 = make_float2((-O3.x + sgn * O3.y) * s2, (-O3.y - sgn * O3.x) * s2);
    v[0] = make_float2(E0.x + O0.x, E0.y + O0.y);
    v[4] = make_float2(E0.x - O0.x, E0.y - O0.y);
    v[1] = make_float2(E1.x + T1.x, E1.y + T1.y);
    v[5] = make_float2(E1.x - T1.x, E1.y - T1.y);
    v[2] = make_float2(E2.x + T2.x, E2.y + T2.y);
    v[6] = make_float2(E2.x - T2.x, E2.y - T2.y);
    v[3] = make_float2(E3.x + T3.x, E3.y + T3.y);
    v[7] = make_float2(E3.x - T3.x, E3.y - T3.y);
}

// apply v[m] *= TW[(m-1)*W + i] (sgn=-1 -> conjugate twiddle), conflict-free
__device__ __forceinline__ void twtbl(float2 v[8], const float2* TW, int W,
                                      int i, float sgn) {
    #pragma unroll
    for (int m = 1; m < 8; ++m) {
        float2 w = TW[(m - 1) * W + i];
        v[m] = cmul(v[m], make_float2(w.x, sgn * w.y));
    }
}

// stage s=8: read Cb[t+64m] (free), dft8, table twiddle, write (4-way)
__device__ __forceinline__ void r8_stage2(float2* Cb, const float2* TW2,
                                          int t, float sgn) {
    float2 u[8];
    #pragma unroll
    for (int m = 0; m < 8; ++m) u[m] = Cb[PC(t + 64 * m)];
    dft8(u, sgn);
    int a = t >> 3;
    twtbl(u, TW2, 8, a, sgn);                          // W_64^{a*m}
    int o1 = 64 * a + (t & 7);
    #pragma unroll
    for (int m = 0; m < 8; ++m) Cb[PC(o1 + 8 * m)] = u[m];
}

// -------- hot GL iteration: one wave per frame; twiddle-power LDS tables
// (lane-major, conflict-free), window from global/L1, fast rcp/sqrt in
// projection. Structure otherwise identical to verified round 9.
__global__ __launch_bounds__(256, 4) void k_gl8(
        const float* __restrict__ Pin, const float* __restrict__ mag,
        const float* __restrict__ envinv,
        const float* __restrict__ gtwr, const float* __restrict__ gtwi,
        const float* __restrict__ win, float* __restrict__ Pout) {
    __shared__ float sigwin[CSPAN];
    __shared__ float2 C[CHUNKF][C_SZ];
    __shared__ float2 TW1[7 * 64];                 // [m-1][t]  = W_512^{t*m}
    __shared__ float2 TW2[7 * 8];                  // [m-1][a]  = W_64^{a*m}
    int blk = blockIdx.x; int b = blk >> 8; int c = blk & (NCHUNK - 1);
    int tid = threadIdx.x; int g = tid >> 6; int t = tid & 63;
    // ---- build twiddle-power tables (504 entries, 2/thread)
    for (int e = tid; e < 7 * 64 + 7 * 8; e += 256) {
        int idx2;
        float2* dst;
        if (e < 7 * 64) {                          // W_512^{tm} = W_1024^{2tm}
            int m1 = e >> 6, tt = e & 63;
            idx2 = 2 * tt * (m1 + 1);              // <= 882
            dst = &TW1[e];
        } else {                                   // W_64^{am} = W_1024^{16am}
            int e2 = e - 7 * 64;
            int m1 = e2 >> 3, a = e2 & 7;
            idx2 = 16 * a * (m1 + 1);              // <= 784
            dst = &TW2[e2];
        }
        float sg = 1.f;
        if (idx2 >= 512) { idx2 -= 512; sg = -1.f; }   // W_1024^{j+512} = -W_1024^j
        *dst = make_float2(sg * gtwr[idx2], sg * gtwi[idx2]);
    }
    // ---- stage normalized signal window (identical to verified round 6)
    const float* Pb = Pin + (size_t)b * NCHUNK * CSPAN;
    for (int q = tid; q < CSPAN; q += 256) {
        float v = Pb[c * CSPAN + q];
        if (q < 768 && c > 0)              v += Pb[(c - 1) * CSPAN + q + 1024];
        if (q >= 1024 && c < NCHUNK - 1)   v += Pb[(c + 1) * CSPAN + q - 1024];
        sigwin[q] = v * envinv[1024 * c + q];
    }
    __syncthreads();
    float2* Cb = C[g];
    const float2* win2 = (const float2*)win;       // global, L1-resident
    int ft = CHUNKF * c + g;
    const float* mrow = mag + (size_t)(b * TFRAMES + ft) * NFREQ;
    // ---- forward stage s=1 fused with z-pack
    float2 v[8];
    #pragma unroll
    for (int m = 0; m < 8; ++m) {
        int mp = t + 64 * m;
        int js = 2 * mp;
        float sv[2];
        #pragma unroll
        for (int h = 0; h < 2; ++h) {
            int pp = 1024 * c + 256 * g + js + h;
            int u = pp - PADW;
            if (u < 0) u = -u;
            else if (u >= LOUT) u = 2 * LOUT - 2 - u;
            sv[h] = sigwin[u + PADW - 1024 * c];
        }
        float2 w2 = win2[mp];
        v[m] = make_float2(sv[0] * w2.x, sv[1] * w2.y);
    }
    dft8(v, +1.f);
    twtbl(v, TW1, 64, t, +1.f);                    // W_512^{t*m}
    #pragma unroll
    for (int m = 0; m < 8; ++m) Cb[PC(8 * t + m)] = v[m];
    r8_stage2(Cb, TW2, t, +1.f);
    // ---- forward stage s=64: Zp in registers, one LDS write-back (free)
    float2 Zp[8];
    #pragma unroll
    for (int m = 0; m < 8; ++m) Zp[m] = Cb[PC(t + 64 * m)];
    dft8(Zp, +1.f);
    #pragma unroll
    for (int m = 0; m < 8; ++m) Cb[PC(t + 64 * m)] = Zp[m];
    // ---- projection; mirror bins JIT from LDS; fast rcp/sqrt (1-ulp class)
    #pragma unroll
    for (int m = 0; m < 8; ++m) {
        int p = t + 64 * m, q = 512 - p;
        float2 Zq = Cb[PC(q & 511)];
        float Ar = 0.5f * (Zp[m].x + Zq.x), Ai = 0.5f * (Zp[m].y - Zq.y);
        float Br = 0.5f * (Zp[m].x - Zq.x), Bi = 0.5f * (Zp[m].y + Zq.y);
        float Wr = gtwr[p & 511], Wi = gtwi[p & 511];
        float P = Wr * Bi + Wi * Br, Q = Wr * Br - Wi * Bi;
        float Xpr = Ar + P, Xpi = Ai - Q;
        float Xqr = Ar - P, Xqi = -Ai - Q;
        float scp = mrow[p] * __builtin_amdgcn_rcpf(
            __builtin_amdgcn_sqrtf(Xpr * Xpr + Xpi * Xpi) + 1e-8f);
        float scq = mrow[q & 1023] * __builtin_amdgcn_rcpf(
            __builtin_amdgcn_sqrtf(Xqr * Xqr + Xqi * Xqi) + 1e-8f);
        float ppr = Xpr * scp, ppi = Xpi * scp;
        float pqr = Xqr * scq, pqi = Xqi * scq;
        float Cr = 0.5f * (ppr + pqr), Ci = 0.5f * (ppi - pqi);
        float Dr = 0.5f * (ppr - pqr), Di = 0.5f * (ppi + pqi);
        float U = Wr * Di - Wi * Dr, V = Wr * Dr + Wi * Di;
        v[m] = make_float2(Cr - U, Ci + V);
    }
    if (t == 0) {
        float2 Z0 = Zp[0];
        float X0 = Z0.x + Z0.y, X512 = Z0.x - Z0.y;
        float p0   = mrow[0]   * X0   * __builtin_amdgcn_rcpf(fabsf(X0)   + 1e-8f);
        float p512 = mrow[512] * X512 * __builtin_amdgcn_rcpf(fabsf(X512) + 1e-8f);
        v[0] = make_float2(0.5f * (p0 + p512), 0.5f * (p0 - p512));
        float2 Zc = Zp[4];
        float X256r = Zc.x, X256i = -Zc.y;
        float sc = mrow[256] * __builtin_amdgcn_rcpf(
            __builtin_amdgcn_sqrtf(X256r * X256r + X256i * X256i) + 1e-8f);
        v[4] = make_float2(X256r * sc, -(X256i * sc));
    }
    // ---- inverse FFT; stage-1 consumes projection registers directly
    dft8(v, -1.f);
    twtbl(v, TW1, 64, t, -1.f);                    // conj for inverse
    #pragma unroll
    for (int m = 0; m < 8; ++m) Cb[PC(8 * t + m)] = v[m];
    r8_stage2(Cb, TW2, t, -1.f);
    // inverse stage s=64 (twiddle-free, in-place; conflict-free pattern)
    {
        float2 u[8];
        #pragma unroll
        for (int m = 0; m < 8; ++m) u[m] = Cb[PC(t + 64 * m)];
        dft8(u, -1.f);
        #pragma unroll
        for (int m = 0; m < 8; ++m) Cb[PC(t + 64 * m)] = u[m];
    }
    __syncthreads();
    // ---- intra-block OLA of 4 frames -> Pout[c]  (x[2m]=re, x[2m+1]=im)
    const float SC = 1.0f / 512.0f;
    float* Po = Pout + ((size_t)b * NCHUNK + c) * CSPAN;
    for (int j = tid; j < CSPAN; j += 256) {
        float acc = 0.f;
        #pragma unroll
        for (int gg = 0; gg < CHUNKF; ++gg) {
            int p = j - 256 * gg;
            if (p >= 0 && p < NFFT) {
                float2 zz = C[gg][PC(p >> 1)];
                float yv = (p & 1) ? zz.y : zz.x;
                acc += yv * win[p];
            }
        }
        Po[j] = acc * SC;
    }
}

// -------------------- final output (verified round 6)
__global__ void k_out(const float* __restrict__ P, const float* __restrict__ envinv,
                      float* __restrict__ out) {
    int i = blockIdx.x * 256 + threadIdx.x;
    int b = blockIdx.y;
    if (i >= LOUT) return;
    int ii = i + PADW;
    int c = ii >> 10; if (c > NCHUNK - 1) c = NCHUNK - 1;
    const float* Pb = P + (size_t)b * NCHUNK * CSPAN;
    int j = ii - 1024 * c;
    float v = Pb[c * CSPAN + j];
    if (c > 0) {
        int j2 = j + 1024;
        if (j2 < CSPAN) v += Pb[(c - 1) * CSPAN + j2];
    }
    out[(size_t)b * LOUT + i] = v * envinv[ii];
}

// ---------------------------------------------------------------------- host
extern "C" void kernel_launch(void* const* d_in, const int* in_sizes, int n_in,
                              void* d_out, int out_size, void* d_ws, size_t ws_size,
                              hipStream_t stream) {
    const float* mel = (const float*)d_in[0];   // (8, 80, 1024)
    const float* ang = (const float*)d_in[1];   // (8, 513, 1024)
    const float* fb  = (const float*)d_in[2];   // (513, 80)
    float* ws = (float*)d_ws;

    float* twr    = ws;                                   // 512   (W_1024)
    float* twi    = twr + NHALF;                          // 512
    float* t5r    = twi + NHALF;                          // 128   (W_512, init)
    float* t5i    = t5r + 128;                            // 128
    float* win    = t5i + 128;                            // 1024
    float* fbT    = win + NFFT;                           // 80*513
    float* envinv = fbT + NMELS * NFREQ;                  // LPAD
    float* mag    = envinv + LPAD;                        // 8*1024*513
    float* PA     = mag + (size_t)BATCH * TFRAMES * NFREQ;    // 8*256*1792
    float* PB     = PA + (size_t)BATCH * NCHUNK * CSPAN;      // 8*256*1792
    float* out    = (float*)d_out;

    k_init_tables<<<4, 256, 0, stream>>>(twr, twi, t5r, t5i, win);
    k_env<<<(LPAD + 255) / 256, 256, 0, stream>>>(win, envinv);
    k_fbt<<<(NFREQ * NMELS + 255) / 256, 256, 0, stream>>>(fb, fbT);
    {
        dim3 g(TFRAMES / 16, BATCH);
        k_mag<<<g, 256, 0, stream>>>(mel, fbT, mag);
    }
    k_init4<<<BATCH * NCHUNK, 512, 0, stream>>>(mag, ang, twr, twi, t5r, t5i, win, PA);

    float* fin = PA;
    float* fout = PB;
    for (int it = 0; it < NITER; ++it) {
        k_gl8<<<BATCH * NCHUNK, 256, 0, stream>>>(fin, mag, envinv, twr, twi,
                                                  win, fout);
        float* tmp = fin; fin = fout; fout = tmp;
    }
    dim3 og((LOUT + 255) / 256, BATCH);
    k_out<<<og, 256, 0, stream>>>(fin, envinv, out);
}

// Round 11
// 1970.154 us; speedup vs baseline: 1.4428x; 1.4428x over previous
//
#include <hip/hip_runtime.h>
#include <math.h>

#define NFFT   1024
#define NHALF  512
#define HOPSZ  256
#define NMELS  80
#define NFREQ  513
#define BATCH  8
#define TFRAMES 1024
#define PADW   512
#define LPAD   (NFFT + (TFRAMES - 1) * HOPSZ)   // 262912
#define LOUT   (LPAD - 2 * PADW)                // 261888
#define NITER  60
#define PI_D   3.14159265358979323846

#define CHUNKF 4                                // frames per chunk
#define CSPAN  1792                             // 1024 + 3*256
#define NCHUNK (TFRAMES / CHUNKF)               // 256

// padding for the (old, init-only) radix-4 FFT
#define PAD(p) ((p) + ((p) >> 5))
#define NPAD   (NHALF + (NHALF >> 5))           // 528

// padding for the hot-loop radix-8 C buffer (float2 units): +1 per 8
#define PC(p)  ((p) + ((p) >> 3))
#define C_SZ   576                              // PC(511)=574 < 576

// ---------------------------------------------------------------- init tables
__global__ void k_init_tables(float* __restrict__ twr, float* __restrict__ twi,
                              float* __restrict__ t5r, float* __restrict__ t5i,
                              float* __restrict__ win) {
    int j = blockIdx.x * 256 + threadIdx.x;
    if (j < NHALF) {
        double th = -2.0 * PI_D * (double)j / (double)NFFT;
        twr[j] = (float)cos(th);
        twi[j] = (float)sin(th);
    }
    if (j < 128) {
        double th = -2.0 * PI_D * (double)j / 512.0;
        t5r[j] = (float)cos(th);
        t5i[j] = (float)sin(th);
    }
    if (j < NFFT) {
        win[j] = (float)(0.5 - 0.5 * cos(2.0 * PI_D * (double)j / (double)NFFT));
    }
}

__global__ void k_env(const float* __restrict__ win, float* __restrict__ envinv) {
    int i = blockIdx.x * 256 + threadIdx.x;
    if (i >= LPAD) return;
    int thi = i / HOPSZ; if (thi > TFRAMES - 1) thi = TFRAMES - 1;
    int d = i - (NFFT - 1);
    int tlo = (d > 0) ? (d + HOPSZ - 1) / HOPSZ : 0;
    float e = 0.f;
    for (int t = tlo; t <= thi; ++t) { float w = win[i - t * HOPSZ]; e += w * w; }
    envinv[i] = (e > 1e-11f) ? (1.0f / e) : 1.0f;
}

__global__ void k_fbt(const float* __restrict__ fb, float* __restrict__ fbT) {
    int i = blockIdx.x * 256 + threadIdx.x;
    if (i < NFREQ * NMELS) {
        int k = i / NMELS, m = i - k * NMELS;
        fbT[m * NFREQ + k] = fb[i];
    }
}

// mag[(b*1024+t)*513+k], tiled 16 t per block
__global__ __launch_bounds__(256) void k_mag(const float* __restrict__ mel,
                                             const float* __restrict__ fbT,
                                             float* __restrict__ mag) {
    __shared__ float sm[NMELS * 16];
    int b = blockIdx.y, t0 = blockIdx.x * 16, tid = threadIdx.x;
    for (int idx = tid; idx < NMELS * 16; idx += 256) {
        int m = idx >> 4, tt = idx & 15;
        sm[idx] = expf(mel[(size_t)(b * NMELS + m) * TFRAMES + (t0 + tt)]);
    }
    __syncthreads();
    for (int k = tid; k < NFREQ; k += 256) {
        float acc[16];
        #pragma unroll
        for (int tt = 0; tt < 16; ++tt) acc[tt] = 0.f;
        for (int m = 0; m < NMELS; ++m) {
            float w = fbT[m * NFREQ + k];
            #pragma unroll
            for (int tt = 0; tt < 16; ++tt) acc[tt] += w * sm[m * 16 + tt];
        }
        #pragma unroll
        for (int tt = 0; tt < 16; ++tt)
            mag[(size_t)((b << 10) + t0 + tt) * NFREQ + k] = fmaxf(acc[tt], 0.f);
    }
}

// ===================== old radix-4 path (init kernel only, verified round 6)
__device__ __forceinline__ void fft512_m(float* xr, float* xi, float* yr, float* yi,
                                         const float* t5r, const float* t5i,
                                         int l, float sgn) {
    float *ar = xr, *ai = xi, *br = yr, *bi = yi;
    #pragma unroll
    for (int st = 0; st < 4; ++st) {
        int s = 1 << (2 * st);
        __syncthreads();
        int j = l;
        int hi = j & ~(s - 1);
        int o1 = j + 3 * hi;
        float v0r = ar[PAD(j)],       v0i = ai[PAD(j)];
        float v1r = ar[PAD(j + 128)], v1i = ai[PAD(j + 128)];
        float v2r = ar[PAD(j + 256)], v2i = ai[PAD(j + 256)];
        float v3r = ar[PAD(j + 384)], v3i = ai[PAD(j + 384)];
        float a_r = v0r + v2r, a_i = v0i + v2i;
        float b_r = v0r - v2r, b_i = v0i - v2i;
        float c_r = v1r + v3r, c_i = v1i + v3i;
        float d_r = v1r - v3r, d_i = v1i - v3i;
        float X0r = a_r + c_r, X0i = a_i + c_i;
        float X2r = a_r - c_r, X2i = a_i - c_i;
        float X1r = b_r + sgn * d_i, X1i = b_i - sgn * d_r;
        float X3r = b_r - sgn * d_i, X3i = b_i + sgn * d_r;
        float w1r = t5r[hi], w1i = sgn * t5i[hi];
        float w2r = w1r * w1r - w1i * w1i, w2i = 2.f * w1r * w1i;
        float w3r = w2r * w1r - w2i * w1i, w3i = w2r * w1i + w2i * w1r;
        br[PAD(o1)]         = X0r;
        bi[PAD(o1)]         = X0i;
        br[PAD(o1 + s)]     = X1r * w1r - X1i * w1i;
        bi[PAD(o1 + s)]     = X1r * w1i + X1i * w1r;
        br[PAD(o1 + 2*s)]   = X2r * w2r - X2i * w2i;
        bi[PAD(o1 + 2*s)]   = X2r * w2i + X2i * w2r;
        br[PAD(o1 + 3*s)]   = X3r * w3r - X3i * w3i;
        bi[PAD(o1 + 3*s)]   = X3r * w3i + X3i * w3r;
        float* t0 = ar; ar = br; br = t0;
        float* t1 = ai; ai = bi; bi = t1;
    }
    __syncthreads();
    #pragma unroll
    for (int r = 0; r < 2; ++r) {
        int j = l + r * 128;
        float x0r = ar[PAD(j)],       x0i = ai[PAD(j)];
        float x1r = ar[PAD(j + 256)], x1i = ai[PAD(j + 256)];
        br[PAD(j)]       = x0r + x1r;
        bi[PAD(j)]       = x0i + x1i;
        br[PAD(j + 256)] = x0r - x1r;
        bi[PAD(j + 256)] = x0i - x1i;
    }
}

__device__ __forceinline__ void chunk_ola4(float (*Yr)[NPAD], float (*Yi)[NPAD],
                                           const float* swin, float* Po, int tid) {
    const float SC = 1.0f / 512.0f;
    for (int j = tid; j < CSPAN; j += 512) {
        float acc = 0.f;
        #pragma unroll
        for (int gg = 0; gg < CHUNKF; ++gg) {
            int p = j - 256 * gg;
            if (p >= 0 && p < NFFT) {
                float yv = (p & 1) ? Yi[gg][PAD(p >> 1)] : Yr[gg][PAD(p >> 1)];
                acc += yv * swin[p];
            }
        }
        Po[j] = acc * SC;
    }
}

// -------------------- init: P0 from mag * e^{i 2pi ang} (verified round 6)
__global__ __launch_bounds__(512) void k_init4(
        const float* __restrict__ mag, const float* __restrict__ ang,
        const float* __restrict__ gtwr, const float* __restrict__ gtwi,
        const float* __restrict__ gt5r, const float* __restrict__ gt5i,
        const float* __restrict__ win, float* __restrict__ Pout) {
    __shared__ float swin[NFFT];
    __shared__ float Xr[CHUNKF][NPAD], Xi[CHUNKF][NPAD];
    __shared__ float Yr[CHUNKF][NPAD], Yi[CHUNKF][NPAD];
    __shared__ float t5r[128], t5i[128];
    int blk = blockIdx.x; int b = blk >> 8; int c = blk & (NCHUNK - 1);
    int tid = threadIdx.x; int g = tid >> 7; int l = tid & 127;
    if (tid < 128) { t5r[tid] = gt5r[tid]; t5i[tid] = gt5i[tid]; }
    for (int q = tid; q < NFFT; q += 512) swin[q] = win[q];
    int ft = CHUNKF * c + g;
    const float* mrow = mag + (size_t)(b * TFRAMES + ft) * NFREQ;
    const float TWO_PI = 6.283185307179586477f;
    if (l == 0) {
        float a0, s0, c0;
        a0 = ang[((size_t)(b * NFREQ + 0)) * TFRAMES + ft] * TWO_PI;
        sincosf(a0, &s0, &c0);
        float p0 = mrow[0] * c0;
        a0 = ang[((size_t)(b * NFREQ + 512)) * TFRAMES + ft] * TWO_PI;
        sincosf(a0, &s0, &c0);
        float p512 = mrow[512] * c0;
        Xr[g][PAD(0)] = 0.5f * (p0 + p512);
        Xi[g][PAD(0)] = 0.5f * (p0 - p512);
        a0 = ang[((size_t)(b * NFREQ + 256)) * TFRAMES + ft] * TWO_PI;
        sincosf(a0, &s0, &c0);
        Xr[g][PAD(256)] = mrow[256] * c0;
        Xi[g][PAD(256)] = -(mrow[256] * s0);
    }
    #pragma unroll
    for (int q2 = 0; q2 < 2; ++q2) {
        int k = l + q2 * 128;
        if (k == 0) continue;
        int j = 512 - k;
        float ak = ang[((size_t)(b * NFREQ + k)) * TFRAMES + ft] * TWO_PI;
        float aj = ang[((size_t)(b * NFREQ + j)) * TFRAMES + ft] * TWO_PI;
        float sk, ck, sj, cj;
        sincosf(ak, &sk, &ck); sincosf(aj, &sj, &cj);
        float pkr = mrow[k] * ck, pki = mrow[k] * sk;
        float pjr = mrow[j] * cj, pji = mrow[j] * sj;
        float Wr = gtwr[k], Wi = gtwi[k];
        float Cr = 0.5f * (pkr + pjr), Ci = 0.5f * (pki - pji);
        float Dr = 0.5f * (pkr - pjr), Di = 0.5f * (pki + pji);
        float U = Wr * Di - Wi * Dr, V = Wr * Dr + Wi * Di;
        Xr[g][PAD(k)] = Cr - U;  Xi[g][PAD(k)] = Ci + V;
        Xr[g][PAD(j)] = Cr + U;  Xi[g][PAD(j)] = -Ci + V;
    }
    fft512_m(Xr[g], Xi[g], Yr[g], Yi[g], t5r, t5i, l, -1.f);
    __syncthreads();
    chunk_ola4(Yr, Yi, swin, Pout + ((size_t)b * NCHUNK + c) * CSPAN, tid);
}

// ===================== wave-local radix-8 machinery (hot loop) ==============
__device__ __forceinline__ float2 cmul(float2 a, float2 b) {
    return make_float2(a.x * b.x - a.y * b.y, a.x * b.y + a.y * b.x);
}

// in-register 8-pt DFT; sgn=+1 forward, -1 inverse (verified round 7)
__device__ __forceinline__ void dft8(float2 v[8], float sgn) {
    const float s2 = 0.70710678118654752f;
    float ar = v[0].x + v[4].x, ai = v[0].y + v[4].y;
    float br = v[0].x - v[4].x, bi = v[0].y - v[4].y;
    float cr = v[2].x + v[6].x, ci = v[2].y + v[6].y;
    float dr = v[2].x - v[6].x, di = v[2].y - v[6].y;
    float2 E0 = make_float2(ar + cr, ai + ci);
    float2 E2 = make_float2(ar - cr, ai - ci);
    float2 E1 = make_float2(br + sgn * di, bi - sgn * dr);
    float2 E3 = make_float2(br - sgn * di, bi + sgn * dr);
    float ar2 = v[1].x + v[5].x, ai2 = v[1].y + v[5].y;
    float br2 = v[1].x - v[5].x, bi2 = v[1].y - v[5].y;
    float cr2 = v[3].x + v[7].x, ci2 = v[3].y + v[7].y;
    float dr2 = v[3].x - v[7].x, di2 = v[3].y - v[7].y;
    float2 O0 = make_float2(ar2 + cr2, ai2 + ci2);
    float2 O2 = make_float2(ar2 - cr2, ai2 - ci2);
    float2 O1 = make_float2(br2 + sgn * di2, bi2 - sgn * dr2);
    float2 O3 = make_float2(br2 - sgn * di2, bi2 + sgn * dr2);
    float2 T1 = make_float2((O1.x + sgn * O1.y) * s2, (O1.y - sgn * O1.x) * s2);
    float2 T2 = make_float2(sgn * O2.y, -sgn * O2.x);
    float2 T3 = make_float2((-O3.x + sgn * O3.y) * s2, (-O3.y - sgn * O3.x) * s2);
    v[0] = make_float2(E0.x + O0.x, E0.y + O0.y);
    v[4] = make_float2(E0.x - O0.x, E0.y - O0.y);
    v[1] = make_float2(E1.x + T1.x, E1.y + T1.y);
    v[5] = make_float2(E1.x - T1.x, E1.y - T1.y);
    v[2] = make_float2(E2.x + T2.x, E2.y + T2.y);
    v[6] = make_float2(E2.x - T2.x, E2.y - T2.y);
    v[3] = make_float2(E3.x + T3.x, E3.y + T3.y);
    v[7] = make_float2(E3.x - T3.x, E3.y - T3.y);
}

// apply v[m] *= W^m for m=1..7, W=(wr,wi)  (low-register sequential chain)
__device__ __forceinline__ void twchain(float2 v[8], float wr, float wi) {
    float2 w = make_float2(wr, wi), cur = w;
    #pragma unroll
    for (int m = 1; m < 8; ++m) { v[m] = cmul(v[m], cur); cur = cmul(cur, w); }
}

// stage s=8: read Cb[t+64m] (free), dft8, twiddle, write Cb[64a+r+8m] (4-way)
__device__ __forceinline__ void r8_stage2(float2* Cb, const float* gtwr,
                                          const float* gtwi, int t, float sgn) {
    float2 u[8];
    #pragma unroll
    for (int m = 0; m < 8; ++m) u[m] = Cb[PC(t + 64 * m)];
    dft8(u, sgn);
    int a = t >> 3;
    twchain(u, gtwr[16 * a], sgn * gtwi[16 * a]);      // W_64^a = W_1024^{16a}
    int o1 = 64 * a + (t & 7);
    #pragma unroll
    for (int m = 0; m < 8; ++m) Cb[PC(o1 + 8 * m)] = u[m];
}

// -------- hot GL iteration (round-9 structure + 3 pressure-reducing changes):
//  (1) sigwin ALIASED into C (z-pack reads -> regs -> barrier -> C overwrite):
//      LDS 29.7KB -> 22.5KB => 7 blocks/CU instead of 5
//  (2) interior chunks (1<=c<=254) have NO reflection -> contiguous float2 z-pack
//  (3) fast v_rcp/v_sqrt in projection (validated round 10, absmax 2e-3)
__global__ __launch_bounds__(256, 4) void k_gl8(
        const float* __restrict__ Pin, const float* __restrict__ mag,
        const float* __restrict__ envinv,
        const float* __restrict__ gtwr, const float* __restrict__ gtwi,
        const float* __restrict__ win, float* __restrict__ Pout) {
    __shared__ __align__(16) unsigned char smem_raw[CHUNKF * C_SZ * sizeof(float2)];
    __shared__ float swin[NFFT];
    float2 (*C)[C_SZ] = reinterpret_cast<float2(*)[C_SZ]>(smem_raw);
    float*  sigwin  = reinterpret_cast<float*>(smem_raw);   // first 7168 B of C
    float2* sigwin2 = reinterpret_cast<float2*>(smem_raw);
    int blk = blockIdx.x; int b = blk >> 8; int c = blk & (NCHUNK - 1);
    int tid = threadIdx.x; int g = tid >> 6; int t = tid & 63;
    // ---- stage normalized signal window (identical to verified round 6)
    const float* Pb = Pin + (size_t)b * NCHUNK * CSPAN;
    for (int q = tid; q < CSPAN; q += 256) {
        float v = Pb[c * CSPAN + q];
        if (q < 768 && c > 0)              v += Pb[(c - 1) * CSPAN + q + 1024];
        if (q >= 1024 && c < NCHUNK - 1)   v += Pb[(c + 1) * CSPAN + q - 1024];
        sigwin[q] = v * envinv[1024 * c + q];
    }
    for (int q = tid; q < NFFT; q += 256) swin[q] = win[q];
    __syncthreads();
    float2* Cb = C[g];
    const float2* swin2 = (const float2*)swin;
    int ft = CHUNKF * c + g;
    const float* mrow = mag + (size_t)(b * TFRAMES + ft) * NFREQ;
    // ---- z-pack into registers: z[m] = s[2mp]w[2mp] + i s[2mp+1]w[2mp+1]
    float2 v[8];
    if (c > 0 && c < NCHUNK - 1) {
        // no reflection possible: q index = 256g + 2mp -> contiguous float2
        #pragma unroll
        for (int m = 0; m < 8; ++m) {
            int mp = t + 64 * m;
            float2 sv = sigwin2[128 * g + mp];
            float2 w2 = swin2[mp];
            v[m] = make_float2(sv.x * w2.x, sv.y * w2.y);
        }
    } else {
        #pragma unroll
        for (int m = 0; m < 8; ++m) {
            int mp = t + 64 * m;
            int js = 2 * mp;
            float sv[2];
            #pragma unroll
            for (int h = 0; h < 2; ++h) {
                int pp = 1024 * c + 256 * g + js + h;
                int u = pp - PADW;
                if (u < 0) u = -u;
                else if (u >= LOUT) u = 2 * LOUT - 2 - u;
                sv[h] = sigwin[u + PADW - 1024 * c];
            }
            float2 w2 = swin2[mp];
            v[m] = make_float2(sv[0] * w2.x, sv[1] * w2.y);
        }
    }
    __syncthreads();   // sigwin fully consumed; C may now overwrite its space
    // ---- forward FFT
    dft8(v, +1.f);
    twchain(v, gtwr[2 * t], gtwi[2 * t]);               // W_512^t
    #pragma unroll
    for (int m = 0; m < 8; ++m) Cb[PC(8 * t + m)] = v[m];
    r8_stage2(Cb, gtwr, gtwi, t, +1.f);
    // ---- forward stage s=64: Zp in registers, one LDS write-back (free)
    float2 Zp[8];
    #pragma unroll
    for (int m = 0; m < 8; ++m) Zp[m] = Cb[PC(t + 64 * m)];
    dft8(Zp, +1.f);
    #pragma unroll
    for (int m = 0; m < 8; ++m) Cb[PC(t + 64 * m)] = Zp[m];
    // ---- projection; mirror bins JIT from LDS; fast rcp/sqrt
    #pragma unroll
    for (int m = 0; m < 8; ++m) {
        int p = t + 64 * m, q = 512 - p;
        float2 Zq = Cb[PC(q & 511)];
        float Ar = 0.5f * (Zp[m].x + Zq.x), Ai = 0.5f * (Zp[m].y - Zq.y);
        float Br = 0.5f * (Zp[m].x - Zq.x), Bi = 0.5f * (Zp[m].y + Zq.y);
        float Wr = gtwr[p & 511], Wi = gtwi[p & 511];
        float P = Wr * Bi + Wi * Br, Q = Wr * Br - Wi * Bi;
        float Xpr = Ar + P, Xpi = Ai - Q;
        float Xqr = Ar - P, Xqi = -Ai - Q;
        float scp = mrow[p] * __builtin_amdgcn_rcpf(
            __builtin_amdgcn_sqrtf(Xpr * Xpr + Xpi * Xpi) + 1e-8f);
        float scq = mrow[q & 1023] * __builtin_amdgcn_rcpf(
            __builtin_amdgcn_sqrtf(Xqr * Xqr + Xqi * Xqi) + 1e-8f);
        float ppr = Xpr * scp, ppi = Xpi * scp;
        float pqr = Xqr * scq, pqi = Xqi * scq;
        float Cr = 0.5f * (ppr + pqr), Ci = 0.5f * (ppi - pqi);
        float Dr = 0.5f * (ppr - pqr), Di = 0.5f * (ppi + pqi);
        float U = Wr * Di - Wi * Dr, V = Wr * Dr + Wi * Di;
        v[m] = make_float2(Cr - U, Ci + V);
    }
    if (t == 0) {
        float2 Z0 = Zp[0];
        float X0 = Z0.x + Z0.y, X512 = Z0.x - Z0.y;
        float p0   = mrow[0]   * X0   * __builtin_amdgcn_rcpf(fabsf(X0)   + 1e-8f);
        float p512 = mrow[512] * X512 * __builtin_amdgcn_rcpf(fabsf(X512) + 1e-8f);
        v[0] = make_float2(0.5f * (p0 + p512), 0.5f * (p0 - p512));
        float2 Zc = Zp[4];
        float X256r = Zc.x, X256i = -Zc.y;
        float sc = mrow[256] * __builtin_amdgcn_rcpf(
            __builtin_amdgcn_sqrtf(X256r * X256r + X256i * X256i) + 1e-8f);
        v[4] = make_float2(X256r * sc, -(X256i * sc));
    }
    // ---- inverse FFT; stage-1 consumes projection registers directly
    dft8(v, -1.f);
    twchain(v, gtwr[2 * t], -gtwi[2 * t]);              // conj for inverse
    #pragma unroll
    for (int m = 0; m < 8; ++m) Cb[PC(8 * t + m)] = v[m];
    r8_stage2(Cb, gtwr, gtwi, t, -1.f);
    // inverse stage s=64 (twiddle-free, in-place; conflict-free pattern)
    {
        float2 u[8];
        #pragma unroll
        for (int m = 0; m < 8; ++m) u[m] = Cb[PC(t + 64 * m)];
        dft8(u, -1.f);
        #pragma unroll
        for (int m = 0; m < 8; ++m) Cb[PC(t + 64 * m)] = u[m];
    }
    __syncthreads();
    // ---- intra-block OLA of 4 frames -> Pout[c]  (x[2m]=re, x[2m+1]=im)
    const float SC = 1.0f / 512.0f;
    float* Po = Pout + ((size_t)b * NCHUNK + c) * CSPAN;
    for (int j = tid; j < CSPAN; j += 256) {
        float acc = 0.f;
        #pragma unroll
        for (int gg = 0; gg < CHUNKF; ++gg) {
            int p = j - 256 * gg;
            if (p >= 0 && p < NFFT) {
                float2 zz = C[gg][PC(p >> 1)];
                float yv = (p & 1) ? zz.y : zz.x;
                acc += yv * swin[p];
            }
        }
        Po[j] = acc * SC;
    }
}

// -------------------- final output (verified round 6)
__global__ void k_out(const float* __restrict__ P, const float* __restrict__ envinv,
                      float* __restrict__ out) {
    int i = blockIdx.x * 256 + threadIdx.x;
    int b = blockIdx.y;
    if (i >= LOUT) return;
    int ii = i + PADW;
    int c = ii >> 10; if (c > NCHUNK - 1) c = NCHUNK - 1;
    const float* Pb = P + (size_t)b * NCHUNK * CSPAN;
    int j = ii - 1024 * c;
    float v = Pb[c * CSPAN + j];
    if (c > 0) {
        int j2 = j + 1024;
        if (j2 < CSPAN) v += Pb[(c - 1) * CSPAN + j2];
    }
    out[(size_t)b * LOUT + i] = v * envinv[ii];
}

// ---------------------------------------------------------------------- host
extern "C" void kernel_launch(void* const* d_in, const int* in_sizes, int n_in,
                              void* d_out, int out_size, void* d_ws, size_t ws_size,
                              hipStream_t stream) {
    const float* mel = (const float*)d_in[0];   // (8, 80, 1024)
    const float* ang = (const float*)d_in[1];   // (8, 513, 1024)
    const float* fb  = (const float*)d_in[2];   // (513, 80)
    float* ws = (float*)d_ws;

    float* twr    = ws;                                   // 512   (W_1024)
    float* twi    = twr + NHALF;                          // 512
    float* t5r    = twi + NHALF;                          // 128   (W_512, init)
    float* t5i    = t5r + 128;                            // 128
    float* win    = t5i + 128;                            // 1024
    float* fbT    = win + NFFT;                           // 80*513
    float* envinv = fbT + NMELS * NFREQ;                  // LPAD
    float* mag    = envinv + LPAD;                        // 8*1024*513
    float* PA     = mag + (size_t)BATCH * TFRAMES * NFREQ;    // 8*256*1792
    float* PB     = PA + (size_t)BATCH * NCHUNK * CSPAN;      // 8*256*1792
    float* out    = (float*)d_out;

    k_init_tables<<<4, 256, 0, stream>>>(twr, twi, t5r, t5i, win);
    k_env<<<(LPAD + 255) / 256, 256, 0, stream>>>(win, envinv);
    k_fbt<<<(NFREQ * NMELS + 255) / 256, 256, 0, stream>>>(fb, fbT);
    {
        dim3 g(TFRAMES / 16, BATCH);
        k_mag<<<g, 256, 0, stream>>>(mel, fbT, mag);
    }
    k_init4<<<BATCH * NCHUNK, 512, 0, stream>>>(mag, ang, twr, twi, t5r, t5i, win, PA);

    float* fin = PA;
    float* fout = PB;
    for (int it = 0; it < NITER; ++it) {
        k_gl8<<<BATCH * NCHUNK, 256, 0, stream>>>(fin, mag, envinv, twr, twi,
                                                  win, fout);
        float* tmp = fin; fin = fout; fout = tmp;
    }
    dim3 og((LOUT + 255) / 256, BATCH);
    k_out<<<og, 256, 0, stream>>>(fin, envinv, out);
}